// Round 11
// baseline (202.800 us; speedup 1.0000x reference)
//
#include <hip/hip_runtime.h>
#include <cstdint>
#include <cstddef>

// Problem constants
#define BB 8
#define TT 1024
#define CC 768
#define NH 12
#define HD 64
// GEMM1: M=8192 N=2304 K=768.  GEMM2: M=8192 N=768 K=768.

using bf16x8 = __attribute__((ext_vector_type(8))) short;  // 8 bf16 (4 VGPRs)
using f32x4  = __attribute__((ext_vector_type(4))) float;  // 4 fp32

static __device__ __forceinline__ short f2bf(float f) {
    uint32_t u;
    __builtin_memcpy(&u, &f, 4);
    u += 0x7FFFu + ((u >> 16) & 1u);   // RNE
    return (short)(u >> 16);
}

static __device__ __forceinline__ uint32_t bfpack(float lo, float hi) {
    return (uint32_t)(uint16_t)f2bf(lo) | ((uint32_t)(uint16_t)f2bf(hi) << 16);
}

#define GLOAD_LDS16(gp, lp)                                                        \
    __builtin_amdgcn_global_load_lds(                                              \
        (const __attribute__((address_space(1))) void*)(gp),                       \
        (__attribute__((address_space(3))) void*)(lp), 16, 0, 0)

// ---------------------------------------------------------------- fc table
__global__ void fc_kernel(float2* __restrict__ fc) {
    int idx = blockIdx.x * 256 + threadIdx.x;   // 32768 = 1024*32
    int t = idx >> 5, p = idx & 31;
    float freq = powf(10000.0f, -(float)p / 32.0f);
    float a = (float)t * freq;
    fc[idx] = make_float2(cosf(a), sinf(a));
}

// ---------------------------------------------------------------- x fp32 -> bf16
__global__ __launch_bounds__(256)
void cast_kernel(const float* __restrict__ in, short* __restrict__ out) {
    int i = (blockIdx.x * 256 + threadIdx.x) * 8;
    float4 f0 = *(const float4*)(in + i);
    float4 f1 = *(const float4*)(in + i + 4);
    bf16x8 h;
    h[0] = f2bf(f0.x); h[1] = f2bf(f0.y); h[2] = f2bf(f0.z); h[3] = f2bf(f0.w);
    h[4] = f2bf(f1.x); h[5] = f2bf(f1.y); h[6] = f2bf(f1.z); h[7] = f2bf(f1.w);
    *(bf16x8*)(out + i) = h;
}

// ------------------------------------------- transpose fp32 [R][C] -> bf16 [C][R]
__global__ __launch_bounds__(256)
void transpose_cast_kernel(const float* __restrict__ in, short* __restrict__ out,
                           int R, int Cdim) {
    __shared__ float tile[32][33];
    int tx = threadIdx.x, ty = threadIdx.y;
    int c0 = blockIdx.x * 32, r0 = blockIdx.y * 32;
#pragma unroll
    for (int i = 0; i < 4; i++)
        tile[ty + 8 * i][tx] = in[(size_t)(r0 + ty + 8 * i) * Cdim + c0 + tx];
    __syncthreads();
#pragma unroll
    for (int i = 0; i < 4; i++)
        out[(size_t)(c0 + ty + 8 * i) * R + r0 + tx] = f2bf(tile[tx][ty + 8 * i]);
}

// ------------------------------------------- V [bh][t][64] -> VT [bh][64][t] (bf16)
__global__ __launch_bounds__(256)
void vtrans_kernel(const short* __restrict__ V, short* __restrict__ VT) {
    __shared__ short tl[64][72];
    const int tid = threadIdx.x;
    const int bh = blockIdx.y, t0 = blockIdx.x * 64;
    {
        int r = tid >> 2, cs = (tid & 3) * 16;
        const short* src = V + (size_t)bh * TT * HD + (size_t)(t0 + r) * HD + cs;
        *(bf16x8*)&tl[r][cs]     = *(const bf16x8*)src;
        *(bf16x8*)&tl[r][cs + 8] = *(const bf16x8*)(src + 8);
    }
    __syncthreads();
    {
        int d = tid >> 2, ts = (tid & 3) * 16;
        bf16x8 o0, o1;
#pragma unroll
        for (int e = 0; e < 8; e++) { o0[e] = tl[ts + e][d]; o1[e] = tl[ts + 8 + e][d]; }
        short* dst = VT + (size_t)bh * TT * HD + (size_t)d * TT + t0 + ts;
        *(bf16x8*)dst       = o0;
        *(bf16x8*)(dst + 8) = o1;
    }
}

// ---------------------------------------------------------------- 256^2 fine-phase GEMM
// m201-style quadrant schedule adapted to K=768. BM=BN=256, BK=32, 512 thr = 8
// waves (2m x 4n), per-wave C = 128x64 (acc[8][4]). LDS 128 KB = ring-4 slots x
// 32 KB {A[256][32] | B[256][32]}. Per K-tile T: TWO fine phases:
//   ph0: ds_read B(4)+A-quad0(4) | STAGE_A(T+3) | barrier | setprio 16-MFMA | barrier
//   ph1: ds_read A-quad1(4)      | STAGE_B(T+3) | barrier | setprio 16-MFMA | vmcnt(8) | barrier
// vmcnt(8) once/tile: 2 issues/phase, keeps last 2 tiles' stages -> retires tile
// T+1's loads exactly before its reads (published by the end barrier). WAR: slot
// (T+3)&3 was last read at tile T-1, closed by its end barrier. B-frags live in
// regs across both phases. Swizzle chunk^=(row&3) both sides (G4 / rule #21).
// End drain vmcnt(0) both EPIs (r6 fix).
template <int EPI>
__global__ __launch_bounds__(512, 2)
void gemm_kernel(const short* __restrict__ Agl, const short* __restrict__ BT,
                 const float* __restrict__ bias,
                 short* __restrict__ Qb, short* __restrict__ Kb, short* __restrict__ Vb,
                 const float2* __restrict__ fc, float* __restrict__ out) {
    __shared__ __align__(16) char smem[131072];   // 128 KB
    const int tid = threadIdx.x;
    const int lane = tid & 63, wid = tid >> 6;
    const int g = lane >> 4, c = lane & 15;
    const int wm = wid >> 2, wn = wid & 3;        // 2 x 4 wave grid

    // bijective XCD swizzle (nwg % 8 == 0: 288 and 96)
    const int nx = gridDim.x;
    const int bid = blockIdx.y * nx + blockIdx.x;
    const int cpx = (nx * gridDim.y) >> 3;
    const int swz = (bid & 7) * cpx + (bid >> 3);
    const int m0 = (swz / nx) * 256, n0 = (swz % nx) * 256;

    // staging: thread covers row (tid>>2) (+128 for instr j=1), 16B chunk (tid&3),
    // source chunk pre-swizzled by row&3 (= (tid>>2)&3). Dest is linear in tid
    // (wave-uniform base + lane*16): dest = slot + j*8192 + tid*16.
    const int sc = (((tid & 3) ^ ((tid >> 2) & 3)) << 3);   // bf16 col offset
    const short* Ab0 = Agl + (size_t)(m0 + (tid >> 2)) * 768 + sc;
    const short* Bb0 = BT  + (size_t)(n0 + (tid >> 2)) * 768 + sc;

#define STAGE_A(S, T)                                                            \
    {                                                                            \
        GLOAD_LDS16(Ab0 + (size_t)(T) * 32,             smem + (S) * 32768 + wid * 1024); \
        GLOAD_LDS16(Ab0 + (size_t)128 * 768 + (T) * 32, smem + (S) * 32768 + 8192 + wid * 1024); \
    }
#define STAGE_B(S, T)                                                            \
    {                                                                            \
        GLOAD_LDS16(Bb0 + (size_t)(T) * 32,             smem + (S) * 32768 + 16384 + wid * 1024); \
        GLOAD_LDS16(Bb0 + (size_t)128 * 768 + (T) * 32, smem + (S) * 32768 + 24576 + wid * 1024); \
    }

    const f32x4 zero4 = {0.f, 0.f, 0.f, 0.f};
    f32x4 acc[8][4];
#pragma unroll
    for (int i = 0; i < 8; i++)
#pragma unroll
        for (int j = 0; j < 4; j++) acc[i][j] = zero4;

    // read-side swizzled 16B chunk within the 64-B row
    const int rk = ((g ^ (c & 3)) << 4);

    // prologue: tiles 0,1,2 -> slots 0,1,2; vmcnt(8) retires tile0
    STAGE_A(0, 0); STAGE_B(0, 0);
    STAGE_A(1, 1); STAGE_B(1, 1);
    STAGE_A(2, 2); STAGE_B(2, 2);
    asm volatile("s_waitcnt vmcnt(8)" ::: "memory");
    asm volatile("s_barrier" ::: "memory");

    for (int t4 = 0; t4 < 24; t4 += 4) {
#pragma unroll
        for (int tt = 0; tt < 4; tt++) {
            const int T = t4 + tt;
            const int slotR = tt;                 // T & 3 (t4 multiple of 4)
            const int slotS = (tt + 3) & 3;
            int Ts = T + 3;
            if (Ts >= 24) Ts -= 24;               // wrap: never read, drained at end
            const char* sA = smem + slotR * 32768;
            const char* sB = sA + 16384;

            // ---- phase 0: B frags (live both phases) + A quad 0
            bf16x8 bfr[4], af[4];
#pragma unroll
            for (int ni = 0; ni < 4; ni++)
                bfr[ni] = *(const bf16x8*)(sB + (wn * 64 + ni * 16 + c) * 64 + rk);
#pragma unroll
            for (int mi = 0; mi < 4; mi++)
                af[mi] = *(const bf16x8*)(sA + (wm * 128 + mi * 16 + c) * 64 + rk);
            STAGE_A(slotS, Ts);
            asm volatile("s_barrier" ::: "memory");
            __builtin_amdgcn_s_setprio(1);
#pragma unroll
            for (int mi = 0; mi < 4; mi++)
#pragma unroll
                for (int ni = 0; ni < 4; ni++)
                    acc[mi][ni] = __builtin_amdgcn_mfma_f32_16x16x32_bf16(
                        af[mi], bfr[ni], acc[mi][ni], 0, 0, 0);
            __builtin_amdgcn_s_setprio(0);
            asm volatile("s_barrier" ::: "memory");

            // ---- phase 1: A quad 1 (B reused from regs)
#pragma unroll
            for (int mi = 0; mi < 4; mi++)
                af[mi] = *(const bf16x8*)(sA + (wm * 128 + (4 + mi) * 16 + c) * 64 + rk);
            STAGE_B(slotS, Ts);
            asm volatile("s_barrier" ::: "memory");
            __builtin_amdgcn_s_setprio(1);
#pragma unroll
            for (int mi = 0; mi < 4; mi++)
#pragma unroll
                for (int ni = 0; ni < 4; ni++)
                    acc[4 + mi][ni] = __builtin_amdgcn_mfma_f32_16x16x32_bf16(
                        af[mi], bfr[ni], acc[4 + mi][ni], 0, 0, 0);
            __builtin_amdgcn_s_setprio(0);
            asm volatile("s_waitcnt vmcnt(8)" ::: "memory");
            asm volatile("s_barrier" ::: "memory");
        }
    }

    // drain ALL outstanding DMAs before LDS reuse / endpgm (r6 race fix)
    asm volatile("s_waitcnt vmcnt(0)" ::: "memory");
    asm volatile("s_barrier" ::: "memory");

    if (EPI == 0) {
        // Phase 1: RoPE on (even,odd) col pairs -> swizzled LDS [256][128 words]
        uint32_t* LD = (uint32_t*)smem;   // 128 KB
#pragma unroll
        for (int ni = 0; ni < 4; ni++) {
            int nl = wn * 64 + ni * 16 + c;
            int n = n0 + nl;
            float bv = bias[n];
            int part = (n >= 1536) ? 2 : (n >= 768 ? 1 : 0);
            int d = (n - part * 768) & 63;
#pragma unroll
            for (int mi = 0; mi < 8; mi++) {
#pragma unroll
                for (int r = 0; r < 4; r++) {
                    int ml = wm * 128 + mi * 16 + g * 4 + r;
                    float v = acc[mi][ni][r] + bv;
                    float pv = __shfl_xor(v, 1);   // partner col n^1 (all lanes exec)
                    if (!(c & 1)) {
                        float o0, o1;
                        if (part < 2) {
                            int t = (m0 + ml) & 1023;
                            float2 cs = fc[t * 32 + (d >> 1)];
                            o0 = v * cs.x - pv * cs.y;
                            o1 = v * cs.y + pv * cs.x;
                            if (part == 0) { o0 *= 0.125f; o1 *= 0.125f; }
                        } else { o0 = v; o1 = pv; }
                        LD[ml * 128 + ((nl >> 1) ^ ((ml & 7) << 2))] = bfpack(o0, o1);
                    }
                }
            }
        }
        __syncthreads();
        // Phase 2: coalesced 16B scatter stores (8 passes x 32 rows).
#pragma unroll
        for (int p = 0; p < 8; p++) {
            int ml = p * 32 + (tid >> 4);
            int sw = (ml & 7) << 2;
            int wc = (tid & 15) * 8;
            int4 d0 = *(const int4*)&LD[ml * 128 + (wc ^ sw)];
            int4 d1 = *(const int4*)&LD[ml * 128 + ((wc + 4) ^ sw)];
            int n = n0 + wc * 2;
            int part = (n >= 1536) ? 2 : (n >= 768 ? 1 : 0);
            int rem = n - part * 768;
            int h = rem >> 6, d = rem & 63;
            int m = m0 + ml, b = m >> 10, t = m & 1023;
            short* dst = (part == 0 ? Qb : part == 1 ? Kb : Vb)
                         + (((size_t)b * NH + h) * TT + t) * HD + d;
            *(int4*)dst = d0;
            *(int4*)(dst + 8) = d1;
        }
    } else {
#pragma unroll
        for (int mi = 0; mi < 8; mi++)
#pragma unroll
            for (int ni = 0; ni < 4; ni++) {
                int n = n0 + wn * 64 + ni * 16 + c;
                float bv = bias[n];
#pragma unroll
                for (int r = 0; r < 4; r++) {
                    int m = m0 + wm * 128 + mi * 16 + g * 4 + r;
                    out[(size_t)m * CC + n] = acc[mi][ni][r] + bv;
                }
            }
    }
#undef STAGE_A
#undef STAGE_B
}

// ---------------------------------------------------------------- flash attention
// (unchanged — passed 6x; swapped-operand S^T = mfma(K,Q), lane-local softmax,
// per-wave barrier-free LDS P-tile, V from global VT, LDS O^T epilogue)
__global__ __launch_bounds__(256)
void attn_kernel(const short* __restrict__ Qb, const short* __restrict__ Kb,
                 const short* __restrict__ VT, short* __restrict__ Ob) {
    __shared__ uint32_t Pt[4][32][32];  // 16 KB per-wave P tile, XOR-swizzled
    __shared__ uint32_t ot[128 * 32];   // 16 KB epilogue O^T transpose
    const int tid = threadIdx.x, lane = tid & 63, wid = tid >> 6;
    const int g = lane >> 4, c = lane & 15;
    const int bh = blockIdx.x, qb = 7 - (int)blockIdx.y;
    const int b = bh / NH, h = bh % NH;
    const short* Qp = Qb + (size_t)bh * TT * HD;
    const short* Kp = Kb + (size_t)bh * TT * HD;
    const short* Vp = VT + (size_t)bh * TT * HD;
    const int q0 = qb * 128 + wid * 32;
    const int sw = (c & 7) << 2;

    bf16x8 qf[2][2];
#pragma unroll
    for (int qs = 0; qs < 2; qs++)
#pragma unroll
        for (int kh = 0; kh < 2; kh++)
            qf[qs][kh] = *(const bf16x8*)(Qp + (size_t)(q0 + qs * 16 + c) * HD + kh * 32 + g * 8);

    const f32x4 zero4 = {0.f, 0.f, 0.f, 0.f};
    f32x4 o[2][4];
#pragma unroll
    for (int qs = 0; qs < 2; qs++)
#pragma unroll
        for (int dt = 0; dt < 4; dt++) o[qs][dt] = zero4;
    float mrun[2] = {-1e30f, -1e30f}, lrun[2] = {0.f, 0.f};

    const int t0max = ((q0 + 31) >> 6) << 6;
    for (int t0 = 0; t0 <= t0max; t0 += 64) {
        f32x4 st[2][4];
#pragma unroll
        for (int nt = 0; nt < 4; nt++) {
            const short* kp = Kp + (size_t)(t0 + nt * 16 + c) * HD + g * 8;
            bf16x8 k0 = *(const bf16x8*)kp;
            bf16x8 k1 = *(const bf16x8*)(kp + 32);
#pragma unroll
            for (int qs = 0; qs < 2; qs++) {
                f32x4 z = zero4;
                z = __builtin_amdgcn_mfma_f32_16x16x32_bf16(k0, qf[qs][0], z, 0, 0, 0);
                z = __builtin_amdgcn_mfma_f32_16x16x32_bf16(k1, qf[qs][1], z, 0, 0, 0);
                st[qs][nt] = z;
            }
        }
        bf16x8 vf[2][4];
#pragma unroll
        for (int blk = 0; blk < 2; blk++)
#pragma unroll
            for (int dt = 0; dt < 4; dt++)
                vf[blk][dt] = *(const bf16x8*)(Vp + (size_t)(dt * 16 + c) * TT + t0 + blk * 32 + g * 8);
        if (t0 + 63 > q0) {
#pragma unroll
            for (int qs = 0; qs < 2; qs++) {
                int q = q0 + qs * 16 + c;
#pragma unroll
                for (int nt = 0; nt < 4; nt++)
#pragma unroll
                    for (int r = 0; r < 4; r++)
                        if (t0 + nt * 16 + g * 4 + r > q) st[qs][nt][r] = -1e30f;
            }
        }
#pragma unroll
        for (int qs = 0; qs < 2; qs++) {
            float mx = st[qs][0][0];
#pragma unroll
            for (int nt = 0; nt < 4; nt++)
#pragma unroll
                for (int r = 0; r < 4; r++) mx = fmaxf(mx, st[qs][nt][r]);
            mx = fmaxf(mx, __shfl_xor(mx, 16));
            mx = fmaxf(mx, __shfl_xor(mx, 32));
            float mnew = fmaxf(mrun[qs], mx);
            float al = __expf(mrun[qs] - mnew);
            mrun[qs] = mnew;
            float sm = 0.f;
#pragma unroll
            for (int nt = 0; nt < 4; nt++)
#pragma unroll
                for (int r = 0; r < 4; r++) {
                    float e = __expf(st[qs][nt][r] - mnew);
                    st[qs][nt][r] = e;
                    sm += e;
                }
            sm += __shfl_xor(sm, 16);
            sm += __shfl_xor(sm, 32);
            lrun[qs] = lrun[qs] * al + sm;
#pragma unroll
            for (int dt = 0; dt < 4; dt++) {
                o[qs][dt][0] *= al; o[qs][dt][1] *= al;
                o[qs][dt][2] *= al; o[qs][dt][3] *= al;
            }
            int row = qs * 16 + c;
#pragma unroll
            for (int nt = 0; nt < 4; nt++) {
                uint32_t w0 = bfpack(st[qs][nt][0], st[qs][nt][1]);
                uint32_t w1 = bfpack(st[qs][nt][2], st[qs][nt][3]);
                int wa = nt * 8 + 2 * g;
                Pt[wid][row][wa ^ sw]       = w0;
                Pt[wid][row][(wa + 1) ^ sw] = w1;
            }
        }
#pragma unroll
        for (int qs = 0; qs < 2; qs++) {
            int row = qs * 16 + c;
#pragma unroll
            for (int blk = 0; blk < 2; blk++) {
                bf16x8 pf = *(const bf16x8*)&Pt[wid][row][(blk * 16 + 4 * g) ^ sw];
#pragma unroll
                for (int dt = 0; dt < 4; dt++)
                    o[qs][dt] = __builtin_amdgcn_mfma_f32_16x16x32_bf16(
                        vf[blk][dt], pf, o[qs][dt], 0, 0, 0);
            }
        }
    }

#pragma unroll
    for (int qs = 0; qs < 2; qs++) {
        float inv = 1.0f / lrun[qs];
        int ql = wid * 32 + qs * 16 + c;
#pragma unroll
        for (int dt = 0; dt < 4; dt++) {
            uint32_t w0 = bfpack(o[qs][dt][0] * inv, o[qs][dt][1] * inv);
            uint32_t w1 = bfpack(o[qs][dt][2] * inv, o[qs][dt][3] * inv);
            int jc0 = dt * 8 + 2 * g;
            int jc1 = jc0 + 1;
            ot[ql * 32 + ((((jc0 >> 2) ^ (c & 7)) << 2) | (jc0 & 3))] = w0;
            ot[ql * 32 + ((((jc1 >> 2) ^ (c & 7)) << 2) | (jc1 & 3))] = w1;
        }
    }
    __syncthreads();
#pragma unroll
    for (int p = 0; p < 4; p++) {
        int q = (tid >> 3) + 32 * p;
        int jb = tid & 7;
        const uint32_t* src = &ot[q * 32 + ((jb ^ (q & 7)) << 2)];
        int4 w = *(const int4*)src;
        *(int4*)(Ob + ((size_t)b * TT + qb * 128 + q) * CC + h * HD + jb * 8) = w;
    }
}

// ---------------------------------------------------------------- launch
extern "C" void kernel_launch(void* const* d_in, const int* in_sizes, int n_in,
                              void* d_out, int out_size, void* d_ws, size_t ws_size,
                              hipStream_t stream) {
    const float* x     = (const float*)d_in[0];
    const float* Wqkv  = (const float*)d_in[1];
    const float* bqkv  = (const float*)d_in[2];
    const float* Wproj = (const float*)d_in[3];
    const float* bproj = (const float*)d_in[4];
    // d_in[5] = mask: causal by construction, unused

    char* ws = (char*)d_ws;
    // ws layout: WqkvT 3538944 | WprojT 1179648 | fc 262144 | Qb | Kb | V/Ob | VbT
    // xb (bf16 x) ALIASES VbT: xb consumed by gemm1, VbT written later by vtrans.
    short*  WqkvT  = (short*)(ws);
    short*  WprojT = (short*)(ws + 3538944);
    float2* fc     = (float2*)(ws + 3538944 + 1179648);
    short*  Qb     = (short*)(ws + 4980736);
    short*  Kb     = (short*)(ws + 4980736 + 1 * 12582912);
    short*  VOb    = (short*)(ws + 4980736 + 2 * 12582912);  // V, then O after vtrans
    short*  VbT    = (short*)(ws + 4980736 + 3 * 12582912);
    short*  xb     = VbT;
    float*  out    = (float*)d_out;

    hipLaunchKernelGGL(fc_kernel, dim3(128), dim3(256), 0, stream, fc);
    hipLaunchKernelGGL(transpose_cast_kernel, dim3(72, 24), dim3(32, 8), 0, stream,
                       Wqkv, WqkvT, 768, 2304);
    hipLaunchKernelGGL(transpose_cast_kernel, dim3(24, 24), dim3(32, 8), 0, stream,
                       Wproj, WprojT, 768, 768);
    hipLaunchKernelGGL(cast_kernel, dim3(3072), dim3(256), 0, stream, x, xb);
    hipLaunchKernelGGL((gemm_kernel<0>), dim3(9, 32), dim3(512), 0, stream,
                       xb, WqkvT, bqkv, Qb, Kb, VOb, fc, (float*)nullptr);
    hipLaunchKernelGGL(vtrans_kernel, dim3(16, 96), dim3(256), 0, stream, VOb, VbT);
    hipLaunchKernelGGL(attn_kernel, dim3(96, 8), dim3(256), 0, stream, Qb, Kb, VbT, VOb);
    hipLaunchKernelGGL((gemm_kernel<1>), dim3(3, 32), dim3(512), 0, stream,
                       VOb, WprojT, bproj,
                       (short*)nullptr, (short*)nullptr, (short*)nullptr,
                       (const float2*)nullptr, out);
}

// Round 12
// 173.154 us; speedup vs baseline: 1.1712x; 1.1712x over previous
//
#include <hip/hip_runtime.h>
#include <cstdint>
#include <cstddef>

// Problem constants
#define BB 8
#define TT 1024
#define CC 768
#define NH 12
#define HD 64
// GEMM1: M=8192 N=2304 K=768.  GEMM2: M=8192 N=768 K=768.

using bf16x8 = __attribute__((ext_vector_type(8))) short;  // 8 bf16 (4 VGPRs)
using f32x4  = __attribute__((ext_vector_type(4))) float;  // 4 fp32

static __device__ __forceinline__ short f2bf(float f) {
    uint32_t u;
    __builtin_memcpy(&u, &f, 4);
    u += 0x7FFFu + ((u >> 16) & 1u);   // RNE
    return (short)(u >> 16);
}

static __device__ __forceinline__ uint32_t bfpack(float lo, float hi) {
    return (uint32_t)(uint16_t)f2bf(lo) | ((uint32_t)(uint16_t)f2bf(hi) << 16);
}

// ---------------------------------------------------------------- fc table
__global__ void fc_kernel(float2* __restrict__ fc) {
    int idx = blockIdx.x * 256 + threadIdx.x;   // 32768 = 1024*32
    int t = idx >> 5, p = idx & 31;
    float freq = powf(10000.0f, -(float)p / 32.0f);
    float a = (float)t * freq;
    fc[idx] = make_float2(cosf(a), sinf(a));
}

// ---------------------------------------------------------------- x fp32 -> bf16
__global__ __launch_bounds__(256)
void cast_kernel(const float* __restrict__ in, short* __restrict__ out) {
    int i = (blockIdx.x * 256 + threadIdx.x) * 8;
    float4 f0 = *(const float4*)(in + i);
    float4 f1 = *(const float4*)(in + i + 4);
    bf16x8 h;
    h[0] = f2bf(f0.x); h[1] = f2bf(f0.y); h[2] = f2bf(f0.z); h[3] = f2bf(f0.w);
    h[4] = f2bf(f1.x); h[5] = f2bf(f1.y); h[6] = f2bf(f1.z); h[7] = f2bf(f1.w);
    *(bf16x8*)(out + i) = h;
}

// ------------------------------------------- transpose fp32 [R][C] -> bf16 [C][R]
__global__ __launch_bounds__(256)
void transpose_cast_kernel(const float* __restrict__ in, short* __restrict__ out,
                           int R, int Cdim) {
    __shared__ float tile[32][33];
    int tx = threadIdx.x, ty = threadIdx.y;
    int c0 = blockIdx.x * 32, r0 = blockIdx.y * 32;
#pragma unroll
    for (int i = 0; i < 4; i++)
        tile[ty + 8 * i][tx] = in[(size_t)(r0 + ty + 8 * i) * Cdim + c0 + tx];
    __syncthreads();
#pragma unroll
    for (int i = 0; i < 4; i++)
        out[(size_t)(c0 + ty + 8 * i) * R + r0 + tx] = f2bf(tile[tx][ty + 8 * i]);
}

// ------------------------------------------- V [bh][t][64] -> VT [bh][64][t] (bf16)
__global__ __launch_bounds__(256)
void vtrans_kernel(const short* __restrict__ V, short* __restrict__ VT) {
    __shared__ short tl[64][72];
    const int tid = threadIdx.x;
    const int bh = blockIdx.y, t0 = blockIdx.x * 64;
    {
        int r = tid >> 2, cs = (tid & 3) * 16;
        const short* src = V + (size_t)bh * TT * HD + (size_t)(t0 + r) * HD + cs;
        *(bf16x8*)&tl[r][cs]     = *(const bf16x8*)src;
        *(bf16x8*)&tl[r][cs + 8] = *(const bf16x8*)(src + 8);
    }
    __syncthreads();
    {
        int d = tid >> 2, ts = (tid & 3) * 16;
        bf16x8 o0, o1;
#pragma unroll
        for (int e = 0; e < 8; e++) { o0[e] = tl[ts + e][d]; o1[e] = tl[ts + 8 + e][d]; }
        short* dst = VT + (size_t)bh * TT * HD + (size_t)d * TT + t0 + ts;
        *(bf16x8*)dst       = o0;
        *(bf16x8*)(dst + 8) = o1;
    }
}

// ---------------------------------------------------------------- reg-staged GEMM
// r12: single-variable test vs r7/r9 — replace global_load_lds with reg-staging
// (global_load_dwordx4 -> VGPR -> ds_write_b128), T14 async-split: loads for
// tile t+1 issued at top of tile t, ds_write after the barrier that closed the
// target buffer's readers. Global reads stay linear (coalesced); XOR swizzle
// moves to the ds_write address; read swizzle = r0-r3 pattern (0 conflicts, r3).
// 128x128 tile, 4 waves (2x2), BK=64, 2x32KB dbuf (64 KB -> 2 blocks/CU).
// No DMA outstanding at endpgm (r6 race class structurally gone).
template <int EPI>
__global__ __launch_bounds__(256, 2)
void gemm_kernel(const short* __restrict__ Agl, const short* __restrict__ BT,
                 const float* __restrict__ bias,
                 short* __restrict__ Qb, short* __restrict__ Kb, short* __restrict__ Vb,
                 const float2* __restrict__ fc, float* __restrict__ out) {
    __shared__ __align__(16) short As[2][128 * 64];   // 32 KB
    __shared__ __align__(16) short Bs[2][128 * 64];   // 32 KB
    const int tid = threadIdx.x;
    const int lane = tid & 63, wid = tid >> 6;
    const int g = lane >> 4, c = lane & 15;
    const int wm = wid >> 1, wn = wid & 1;

    // bijective XCD swizzle (nwg % 8 == 0: 1152 and 384)
    const int nx = gridDim.x;
    const int bid = blockIdx.y * nx + blockIdx.x;
    const int cpx = (nx * gridDim.y) >> 3;
    const int swz = (bid & 7) * cpx + (bid >> 3);
    const int m0 = (swz / nx) * 128, n0 = (swz % nx) * 128;

    // staging map: 4 (q,h) instrs per matrix; row_l = wid*32 + q*16 + (lane>>2),
    // global 16B chunk = (lane&3) + h*4 (linear -> coalesced 64B per 4 lanes).
    const int srow = lane >> 2;       // 0..15
    const int sch = lane & 3;
    const short* Ab0 = Agl + (size_t)(m0 + wid * 32 + srow) * 768 + sch * 8;
    const short* Bb0 = BT  + (size_t)(n0 + wid * 32 + srow) * 768 + sch * 8;

    const f32x4 zero4 = {0.f, 0.f, 0.f, 0.f};
    f32x4 acc[4][4];
#pragma unroll
    for (int i = 0; i < 4; i++)
#pragma unroll
        for (int j = 0; j < 4; j++) acc[i][j] = zero4;

    bf16x8 rA[4], rB[4];
    // LOAD(kt): issue 8 global loads for tile kt into regs
#define LOAD(kt)                                                               \
    {                                                                          \
        size_t ko = (size_t)(kt) * 64;                                         \
        _Pragma("unroll")                                                      \
        for (int q = 0; q < 2; q++)                                            \
            _Pragma("unroll")                                                  \
            for (int h = 0; h < 2; h++) {                                      \
                rA[q * 2 + h] = *(const bf16x8*)(Ab0 + (size_t)q * 16 * 768 + ko + h * 32); \
                rB[q * 2 + h] = *(const bf16x8*)(Bb0 + (size_t)q * 16 * 768 + ko + h * 32); \
            }                                                                  \
    }
    // WRITE(buf): regs -> LDS, XOR-swizzled (chunk ^ (row&7))
#define WRITE(buf)                                                             \
    {                                                                          \
        _Pragma("unroll")                                                      \
        for (int q = 0; q < 2; q++)                                            \
            _Pragma("unroll")                                                  \
            for (int h = 0; h < 2; h++) {                                      \
                int row = wid * 32 + q * 16 + srow;                            \
                int ci = sch + h * 4;                                          \
                int idx = row * 64 + ((ci ^ (row & 7)) * 8);                   \
                *(bf16x8*)&As[buf][idx] = rA[q * 2 + h];                       \
                *(bf16x8*)&Bs[buf][idx] = rB[q * 2 + h];                       \
            }                                                                  \
    }
    // COMPUTE(buf): 2 kh x 16 MFMA from swizzled LDS
#define COMPUTE(buf)                                                           \
    {                                                                          \
        _Pragma("unroll")                                                      \
        for (int kk = 0; kk < 2; kk++) {                                       \
            bf16x8 af[4], bfr[4];                                              \
            _Pragma("unroll")                                                  \
            for (int mi = 0; mi < 4; mi++) {                                   \
                int row = wm * 64 + mi * 16 + c;                               \
                af[mi] = *(const bf16x8*)&As[buf][row * 64 + (((kk * 4 + g) ^ (row & 7)) * 8)]; \
            }                                                                  \
            _Pragma("unroll")                                                  \
            for (int ni = 0; ni < 4; ni++) {                                   \
                int row = wn * 64 + ni * 16 + c;                               \
                bfr[ni] = *(const bf16x8*)&Bs[buf][row * 64 + (((kk * 4 + g) ^ (row & 7)) * 8)]; \
            }                                                                  \
            __builtin_amdgcn_s_setprio(1);                                     \
            _Pragma("unroll")                                                  \
            for (int mi = 0; mi < 4; mi++)                                     \
                _Pragma("unroll")                                              \
                for (int ni = 0; ni < 4; ni++)                                 \
                    acc[mi][ni] = __builtin_amdgcn_mfma_f32_16x16x32_bf16(     \
                        af[mi], bfr[ni], acc[mi][ni], 0, 0, 0);                \
            __builtin_amdgcn_s_setprio(0);                                     \
        }                                                                      \
    }

    // prologue: tile0 -> buf0
    LOAD(0);
    WRITE(0);
    __syncthreads();

    // 12 tiles, unrolled by 2 for static buffer indices
#pragma unroll 1
    for (int t2 = 0; t2 < 12; t2 += 2) {
        // tile t2 (buf0): issue loads t2+1 early (T14), compute, swap
        LOAD(t2 + 1);
        COMPUTE(0);
        __syncthreads();          // closes reads of buf0 & buf1-writes visible
        WRITE(1);                 // buf1 last read at t2-1 (closed above)
        __syncthreads();          // publish buf1
        // tile t2+1 (buf1)
        if (t2 + 2 < 12) {
            LOAD(t2 + 2);
            COMPUTE(1);
            __syncthreads();
            WRITE(0);
            __syncthreads();
        } else {
            COMPUTE(1);
        }
    }

    if (EPI == 0) {
        __syncthreads();   // all compute done before LDS reuse
        // Phase 1: RoPE on (even,odd) col pairs -> swizzled LDS [128][64 words]
        uint32_t* LD = (uint32_t*)&As[0][0];   // 32 KB
#pragma unroll
        for (int ni = 0; ni < 4; ni++) {
            int nl = wn * 64 + ni * 16 + c;
            int n = n0 + nl;
            float bv = bias[n];
            int part = (n >= 1536) ? 2 : (n >= 768 ? 1 : 0);
            int d = (n - part * 768) & 63;
#pragma unroll
            for (int mi = 0; mi < 4; mi++) {
#pragma unroll
                for (int r = 0; r < 4; r++) {
                    int ml = wm * 64 + mi * 16 + g * 4 + r;
                    float v = acc[mi][ni][r] + bv;
                    float pv = __shfl_xor(v, 1);   // partner col n^1 (all lanes exec)
                    if (!(c & 1)) {
                        float o0, o1;
                        if (part < 2) {
                            int t = (m0 + ml) & 1023;
                            float2 cs = fc[t * 32 + (d >> 1)];
                            o0 = v * cs.x - pv * cs.y;
                            o1 = v * cs.y + pv * cs.x;
                            if (part == 0) { o0 *= 0.125f; o1 *= 0.125f; }
                        } else { o0 = v; o1 = pv; }
                        LD[ml * 64 + ((nl >> 1) ^ (((ml >> 2) & 3) << 3))] = bfpack(o0, o1);
                    }
                }
            }
        }
        __syncthreads();
        // Phase 2: coalesced 16B scatter stores.
#pragma unroll
        for (int p = 0; p < 8; p++) {
            int ml = p * 16 + (tid >> 4);
            int wc = (tid & 15) * 4;
            int4 dat = *(const int4*)&LD[ml * 64 + (wc ^ (((ml >> 2) & 3) << 3))];
            int n = n0 + wc * 2;
            int part = (n >= 1536) ? 2 : (n >= 768 ? 1 : 0);
            int rem = n - part * 768;
            int h = rem >> 6, d = rem & 63;
            int m = m0 + ml, b = m >> 10, t = m & 1023;
            short* dst = (part == 0 ? Qb : part == 1 ? Kb : Vb)
                         + (((size_t)b * NH + h) * TT + t) * HD + d;
            *(int4*)dst = dat;
        }
    } else {
#pragma unroll
        for (int mi = 0; mi < 4; mi++)
#pragma unroll
            for (int ni = 0; ni < 4; ni++) {
                int n = n0 + wn * 64 + ni * 16 + c;
                float bv = bias[n];
#pragma unroll
                for (int r = 0; r < 4; r++) {
                    int m = m0 + wm * 64 + mi * 16 + g * 4 + r;
                    out[(size_t)m * CC + n] = acc[mi][ni][r] + bv;
                }
            }
    }
#undef LOAD
#undef WRITE
#undef COMPUTE
}

// ---------------------------------------------------------------- flash attention
// (unchanged — passed 7x; swapped-operand S^T = mfma(K,Q), lane-local softmax,
// per-wave barrier-free LDS P-tile, V from global VT, LDS O^T epilogue)
__global__ __launch_bounds__(256)
void attn_kernel(const short* __restrict__ Qb, const short* __restrict__ Kb,
                 const short* __restrict__ VT, short* __restrict__ Ob) {
    __shared__ uint32_t Pt[4][32][32];  // 16 KB per-wave P tile, XOR-swizzled
    __shared__ uint32_t ot[128 * 32];   // 16 KB epilogue O^T transpose
    const int tid = threadIdx.x, lane = tid & 63, wid = tid >> 6;
    const int g = lane >> 4, c = lane & 15;
    const int bh = blockIdx.x, qb = 7 - (int)blockIdx.y;
    const int b = bh / NH, h = bh % NH;
    const short* Qp = Qb + (size_t)bh * TT * HD;
    const short* Kp = Kb + (size_t)bh * TT * HD;
    const short* Vp = VT + (size_t)bh * TT * HD;
    const int q0 = qb * 128 + wid * 32;
    const int sw = (c & 7) << 2;

    bf16x8 qf[2][2];
#pragma unroll
    for (int qs = 0; qs < 2; qs++)
#pragma unroll
        for (int kh = 0; kh < 2; kh++)
            qf[qs][kh] = *(const bf16x8*)(Qp + (size_t)(q0 + qs * 16 + c) * HD + kh * 32 + g * 8);

    const f32x4 zero4 = {0.f, 0.f, 0.f, 0.f};
    f32x4 o[2][4];
#pragma unroll
    for (int qs = 0; qs < 2; qs++)
#pragma unroll
        for (int dt = 0; dt < 4; dt++) o[qs][dt] = zero4;
    float mrun[2] = {-1e30f, -1e30f}, lrun[2] = {0.f, 0.f};

    const int t0max = ((q0 + 31) >> 6) << 6;
    for (int t0 = 0; t0 <= t0max; t0 += 64) {
        f32x4 st[2][4];
#pragma unroll
        for (int nt = 0; nt < 4; nt++) {
            const short* kp = Kp + (size_t)(t0 + nt * 16 + c) * HD + g * 8;
            bf16x8 k0 = *(const bf16x8*)kp;
            bf16x8 k1 = *(const bf16x8*)(kp + 32);
#pragma unroll
            for (int qs = 0; qs < 2; qs++) {
                f32x4 z = zero4;
                z = __builtin_amdgcn_mfma_f32_16x16x32_bf16(k0, qf[qs][0], z, 0, 0, 0);
                z = __builtin_amdgcn_mfma_f32_16x16x32_bf16(k1, qf[qs][1], z, 0, 0, 0);
                st[qs][nt] = z;
            }
        }
        bf16x8 vf[2][4];
#pragma unroll
        for (int blk = 0; blk < 2; blk++)
#pragma unroll
            for (int dt = 0; dt < 4; dt++)
                vf[blk][dt] = *(const bf16x8*)(Vp + (size_t)(dt * 16 + c) * TT + t0 + blk * 32 + g * 8);
        if (t0 + 63 > q0) {
#pragma unroll
            for (int qs = 0; qs < 2; qs++) {
                int q = q0 + qs * 16 + c;
#pragma unroll
                for (int nt = 0; nt < 4; nt++)
#pragma unroll
                    for (int r = 0; r < 4; r++)
                        if (t0 + nt * 16 + g * 4 + r > q) st[qs][nt][r] = -1e30f;
            }
        }
#pragma unroll
        for (int qs = 0; qs < 2; qs++) {
            float mx = st[qs][0][0];
#pragma unroll
            for (int nt = 0; nt < 4; nt++)
#pragma unroll
                for (int r = 0; r < 4; r++) mx = fmaxf(mx, st[qs][nt][r]);
            mx = fmaxf(mx, __shfl_xor(mx, 16));
            mx = fmaxf(mx, __shfl_xor(mx, 32));
            float mnew = fmaxf(mrun[qs], mx);
            float al = __expf(mrun[qs] - mnew);
            mrun[qs] = mnew;
            float sm = 0.f;
#pragma unroll
            for (int nt = 0; nt < 4; nt++)
#pragma unroll
                for (int r = 0; r < 4; r++) {
                    float e = __expf(st[qs][nt][r] - mnew);
                    st[qs][nt][r] = e;
                    sm += e;
                }
            sm += __shfl_xor(sm, 16);
            sm += __shfl_xor(sm, 32);
            lrun[qs] = lrun[qs] * al + sm;
#pragma unroll
            for (int dt = 0; dt < 4; dt++) {
                o[qs][dt][0] *= al; o[qs][dt][1] *= al;
                o[qs][dt][2] *= al; o[qs][dt][3] *= al;
            }
            int row = qs * 16 + c;
#pragma unroll
            for (int nt = 0; nt < 4; nt++) {
                uint32_t w0 = bfpack(st[qs][nt][0], st[qs][nt][1]);
                uint32_t w1 = bfpack(st[qs][nt][2], st[qs][nt][3]);
                int wa = nt * 8 + 2 * g;
                Pt[wid][row][wa ^ sw]       = w0;
                Pt[wid][row][(wa + 1) ^ sw] = w1;
            }
        }
#pragma unroll
        for (int qs = 0; qs < 2; qs++) {
            int row = qs * 16 + c;
#pragma unroll
            for (int blk = 0; blk < 2; blk++) {
                bf16x8 pf = *(const bf16x8*)&Pt[wid][row][(blk * 16 + 4 * g) ^ sw];
#pragma unroll
                for (int dt = 0; dt < 4; dt++)
                    o[qs][dt] = __builtin_amdgcn_mfma_f32_16x16x32_bf16(
                        vf[blk][dt], pf, o[qs][dt], 0, 0, 0);
            }
        }
    }

#pragma unroll
    for (int qs = 0; qs < 2; qs++) {
        float inv = 1.0f / lrun[qs];
        int ql = wid * 32 + qs * 16 + c;
#pragma unroll
        for (int dt = 0; dt < 4; dt++) {
            uint32_t w0 = bfpack(o[qs][dt][0] * inv, o[qs][dt][1] * inv);
            uint32_t w1 = bfpack(o[qs][dt][2] * inv, o[qs][dt][3] * inv);
            int jc0 = dt * 8 + 2 * g;
            int jc1 = jc0 + 1;
            ot[ql * 32 + ((((jc0 >> 2) ^ (c & 7)) << 2) | (jc0 & 3))] = w0;
            ot[ql * 32 + ((((jc1 >> 2) ^ (c & 7)) << 2) | (jc1 & 3))] = w1;
        }
    }
    __syncthreads();
#pragma unroll
    for (int p = 0; p < 4; p++) {
        int q = (tid >> 3) + 32 * p;
        int jb = tid & 7;
        const uint32_t* src = &ot[q * 32 + ((jb ^ (q & 7)) << 2)];
        int4 w = *(const int4*)src;
        *(int4*)(Ob + ((size_t)b * TT + qb * 128 + q) * CC + h * HD + jb * 8) = w;
    }
}

// ---------------------------------------------------------------- launch
extern "C" void kernel_launch(void* const* d_in, const int* in_sizes, int n_in,
                              void* d_out, int out_size, void* d_ws, size_t ws_size,
                              hipStream_t stream) {
    const float* x     = (const float*)d_in[0];
    const float* Wqkv  = (const float*)d_in[1];
    const float* bqkv  = (const float*)d_in[2];
    const float* Wproj = (const float*)d_in[3];
    const float* bproj = (const float*)d_in[4];
    // d_in[5] = mask: causal by construction, unused

    char* ws = (char*)d_ws;
    // ws layout: WqkvT 3538944 | WprojT 1179648 | fc 262144 | Qb | Kb | V/Ob | VbT
    // xb (bf16 x) ALIASES VbT: xb consumed by gemm1, VbT written later by vtrans.
    short*  WqkvT  = (short*)(ws);
    short*  WprojT = (short*)(ws + 3538944);
    float2* fc     = (float2*)(ws + 3538944 + 1179648);
    short*  Qb     = (short*)(ws + 4980736);
    short*  Kb     = (short*)(ws + 4980736 + 1 * 12582912);
    short*  VOb    = (short*)(ws + 4980736 + 2 * 12582912);  // V, then O after vtrans
    short*  VbT    = (short*)(ws + 4980736 + 3 * 12582912);
    short*  xb     = VbT;
    float*  out    = (float*)d_out;

    hipLaunchKernelGGL(fc_kernel, dim3(128), dim3(256), 0, stream, fc);
    hipLaunchKernelGGL(transpose_cast_kernel, dim3(72, 24), dim3(32, 8), 0, stream,
                       Wqkv, WqkvT, 768, 2304);
    hipLaunchKernelGGL(transpose_cast_kernel, dim3(24, 24), dim3(32, 8), 0, stream,
                       Wproj, WprojT, 768, 768);
    hipLaunchKernelGGL(cast_kernel, dim3(3072), dim3(256), 0, stream, x, xb);
    hipLaunchKernelGGL((gemm_kernel<0>), dim3(18, 64), dim3(256), 0, stream,
                       xb, WqkvT, bqkv, Qb, Kb, VOb, fc, (float*)nullptr);
    hipLaunchKernelGGL(vtrans_kernel, dim3(16, 96), dim3(256), 0, stream, VOb, VbT);
    hipLaunchKernelGGL(attn_kernel, dim3(96, 8), dim3(256), 0, stream, Qb, Kb, VbT, VOb);
    hipLaunchKernelGGL((gemm_kernel<1>), dim3(6, 64), dim3(256), 0, stream,
                       VOb, WprojT, bproj,
                       (short*)nullptr, (short*)nullptr, (short*)nullptr,
                       (const float2*)nullptr, out);
}

// Round 13
// 163.035 us; speedup vs baseline: 1.2439x; 1.0621x over previous
//
#include <hip/hip_runtime.h>
#include <cstdint>
#include <cstddef>
#include <cstring>

// Problem constants
#define BB 8
#define TT 1024
#define CC 768
#define NH 12
#define HD 64
// GEMM1: M=8192 N=2304 K=768.  GEMM2: M=8192 N=768 K=768.

using bf16x8 = __attribute__((ext_vector_type(8))) short;  // 8 bf16 (4 VGPRs)
using f32x4  = __attribute__((ext_vector_type(4))) float;  // 4 fp32

static __device__ __forceinline__ short f2bf(float f) {
    uint32_t u;
    __builtin_memcpy(&u, &f, 4);
    u += 0x7FFFu + ((u >> 16) & 1u);   // RNE
    return (short)(u >> 16);
}

static __device__ __forceinline__ uint32_t bfpack(float lo, float hi) {
    return (uint32_t)(uint16_t)f2bf(lo) | ((uint32_t)(uint16_t)f2bf(hi) << 16);
}

// ---------------------------------------------------------------- merged prep
// bid ranges: [0,1728) Wqkv transpose | [1728,2304) Wproj transpose |
// [2304,5376) x cast | [5376,5504) fc table.
__global__ __launch_bounds__(256)
void prep_kernel(const float* __restrict__ x, const float* __restrict__ Wqkv,
                 const float* __restrict__ Wproj,
                 short* __restrict__ WqkvT, short* __restrict__ WprojT,
                 short* __restrict__ xb, float2* __restrict__ fc) {
    __shared__ float tile[32][33];
    const int tid = threadIdx.x;
    int bid = blockIdx.x;
    if (bid < 2304) {
        // transpose_cast fp32 [768][Cdim] -> bf16 [Cdim][768]
        const float* in;
        short* out;
        int Cdim, bx, by;
        if (bid < 1728) { in = Wqkv; out = WqkvT; Cdim = 2304; bx = bid % 72; by = bid / 72; }
        else { int b2 = bid - 1728; in = Wproj; out = WprojT; Cdim = 768; bx = b2 % 24; by = b2 / 24; }
        int tx = tid & 31, ty = tid >> 5;
        int c0 = bx * 32, r0 = by * 32;
#pragma unroll
        for (int i = 0; i < 4; i++)
            tile[ty + 8 * i][tx] = in[(size_t)(r0 + ty + 8 * i) * Cdim + c0 + tx];
        __syncthreads();
#pragma unroll
        for (int i = 0; i < 4; i++)
            out[(size_t)(c0 + ty + 8 * i) * 768 + r0 + tx] = f2bf(tile[tx][ty + 8 * i]);
    } else if (bid < 5376) {
        int i = ((bid - 2304) * 256 + tid) * 8;
        float4 f0 = *(const float4*)(x + i);
        float4 f1 = *(const float4*)(x + i + 4);
        bf16x8 h;
        h[0] = f2bf(f0.x); h[1] = f2bf(f0.y); h[2] = f2bf(f0.z); h[3] = f2bf(f0.w);
        h[4] = f2bf(f1.x); h[5] = f2bf(f1.y); h[6] = f2bf(f1.z); h[7] = f2bf(f1.w);
        *(bf16x8*)(xb + i) = h;
    } else {
        int idx = (bid - 5376) * 256 + tid;   // 32768 = 1024*32
        int t = idx >> 5, p = idx & 31;
        float freq = powf(10000.0f, -(float)p / 32.0f);
        float a = (float)t * freq;
        fc[idx] = make_float2(cosf(a), sinf(a));
    }
}

// ---------------------------------------------------------------- reg-staged GEMM
// K-loop byte-identical to r12 (passed, best-equal perf, no DMA at endpgm).
// EPI 0: RoPE repack -> Q/K scatter; V-strips (n0>=1536, block-uniform) write
//        VT[bh][d][t] DIRECTLY via column extraction from the LDS repack
//        (fused vtrans). EPI 1: bias + fp32 LDS repack -> dwordx4 stores.
template <int EPI>
__global__ __launch_bounds__(256, 2)
void gemm_kernel(const short* __restrict__ Agl, const short* __restrict__ BT,
                 const float* __restrict__ bias,
                 short* __restrict__ Qb, short* __restrict__ Kb, short* __restrict__ VT,
                 const float2* __restrict__ fc, float* __restrict__ out) {
    __shared__ __align__(16) short smem_s[4 * 128 * 64];   // 64 KB
    short (*As)[128 * 64] = (short(*)[128 * 64])smem_s;
    short (*Bs)[128 * 64] = (short(*)[128 * 64])(smem_s + 2 * 128 * 64);
    const int tid = threadIdx.x;
    const int lane = tid & 63, wid = tid >> 6;
    const int g = lane >> 4, c = lane & 15;
    const int wm = wid >> 1, wn = wid & 1;

    // bijective XCD swizzle (nwg % 8 == 0: 1152 and 384)
    const int nx = gridDim.x;
    const int bid = blockIdx.y * nx + blockIdx.x;
    const int cpx = (nx * gridDim.y) >> 3;
    const int swz = (bid & 7) * cpx + (bid >> 3);
    const int m0 = (swz / nx) * 128, n0 = (swz % nx) * 128;

    const int srow = lane >> 2;       // 0..15
    const int sch = lane & 3;
    const short* Ab0 = Agl + (size_t)(m0 + wid * 32 + srow) * 768 + sch * 8;
    const short* Bb0 = BT  + (size_t)(n0 + wid * 32 + srow) * 768 + sch * 8;

    const f32x4 zero4 = {0.f, 0.f, 0.f, 0.f};
    f32x4 acc[4][4];
#pragma unroll
    for (int i = 0; i < 4; i++)
#pragma unroll
        for (int j = 0; j < 4; j++) acc[i][j] = zero4;

    bf16x8 rA[4], rB[4];
#define LOAD(kt)                                                               \
    {                                                                          \
        size_t ko = (size_t)(kt) * 64;                                         \
        _Pragma("unroll")                                                      \
        for (int q = 0; q < 2; q++)                                            \
            _Pragma("unroll")                                                  \
            for (int h = 0; h < 2; h++) {                                      \
                rA[q * 2 + h] = *(const bf16x8*)(Ab0 + (size_t)q * 16 * 768 + ko + h * 32); \
                rB[q * 2 + h] = *(const bf16x8*)(Bb0 + (size_t)q * 16 * 768 + ko + h * 32); \
            }                                                                  \
    }
#define WRITE(buf)                                                             \
    {                                                                          \
        _Pragma("unroll")                                                      \
        for (int q = 0; q < 2; q++)                                            \
            _Pragma("unroll")                                                  \
            for (int h = 0; h < 2; h++) {                                      \
                int row = wid * 32 + q * 16 + srow;                            \
                int ci = sch + h * 4;                                          \
                int idx = row * 64 + ((ci ^ (row & 7)) * 8);                   \
                *(bf16x8*)&As[buf][idx] = rA[q * 2 + h];                       \
                *(bf16x8*)&Bs[buf][idx] = rB[q * 2 + h];                       \
            }                                                                  \
    }
#define COMPUTE(buf)                                                           \
    {                                                                          \
        _Pragma("unroll")                                                      \
        for (int kk = 0; kk < 2; kk++) {                                       \
            bf16x8 af[4], bfr[4];                                              \
            _Pragma("unroll")                                                  \
            for (int mi = 0; mi < 4; mi++) {                                   \
                int row = wm * 64 + mi * 16 + c;                               \
                af[mi] = *(const bf16x8*)&As[buf][row * 64 + (((kk * 4 + g) ^ (row & 7)) * 8)]; \
            }                                                                  \
            _Pragma("unroll")                                                  \
            for (int ni = 0; ni < 4; ni++) {                                   \
                int row = wn * 64 + ni * 16 + c;                               \
                bfr[ni] = *(const bf16x8*)&Bs[buf][row * 64 + (((kk * 4 + g) ^ (row & 7)) * 8)]; \
            }                                                                  \
            __builtin_amdgcn_s_setprio(1);                                     \
            _Pragma("unroll")                                                  \
            for (int mi = 0; mi < 4; mi++)                                     \
                _Pragma("unroll")                                              \
                for (int ni = 0; ni < 4; ni++)                                 \
                    acc[mi][ni] = __builtin_amdgcn_mfma_f32_16x16x32_bf16(     \
                        af[mi], bfr[ni], acc[mi][ni], 0, 0, 0);                \
            __builtin_amdgcn_s_setprio(0);                                     \
        }                                                                      \
    }

    LOAD(0);
    WRITE(0);
    __syncthreads();

#pragma unroll 1
    for (int t2 = 0; t2 < 12; t2 += 2) {
        LOAD(t2 + 1);
        COMPUTE(0);
        __syncthreads();
        WRITE(1);
        __syncthreads();
        if (t2 + 2 < 12) {
            LOAD(t2 + 2);
            COMPUTE(1);
            __syncthreads();
            WRITE(0);
            __syncthreads();
        } else {
            COMPUTE(1);
        }
    }
    __syncthreads();   // all waves done reading LDS before epilogue reuse

    if (EPI == 0) {
        // Phase 1: RoPE on (even,odd) col pairs -> swizzled LDS [128][64 words]
        uint32_t* LD = (uint32_t*)smem_s;   // 32 KB
#pragma unroll
        for (int ni = 0; ni < 4; ni++) {
            int nl = wn * 64 + ni * 16 + c;
            int n = n0 + nl;
            float bv = bias[n];
            int part = (n >= 1536) ? 2 : (n >= 768 ? 1 : 0);
            int d = (n - part * 768) & 63;
#pragma unroll
            for (int mi = 0; mi < 4; mi++) {
#pragma unroll
                for (int r = 0; r < 4; r++) {
                    int ml = wm * 64 + mi * 16 + g * 4 + r;
                    float v = acc[mi][ni][r] + bv;
                    float pv = __shfl_xor(v, 1);   // partner col n^1 (all lanes exec)
                    if (!(c & 1)) {
                        float o0, o1;
                        if (part < 2) {
                            int t = (m0 + ml) & 1023;
                            float2 cs = fc[t * 32 + (d >> 1)];
                            o0 = v * cs.x - pv * cs.y;
                            o1 = v * cs.y + pv * cs.x;
                            if (part == 0) { o0 *= 0.125f; o1 *= 0.125f; }
                        } else { o0 = v; o1 = pv; }
                        LD[ml * 64 + ((nl >> 1) ^ (((ml >> 2) & 3) << 3))] = bfpack(o0, o1);
                    }
                }
            }
        }
        __syncthreads();
        if (n0 >= 1536) {
            // V-strip: write VT[bh][d][t] directly (fused vtrans).
            // LD col wc holds cols (2wc, 2wc+1) = head h0+(wc>>5), d0=(2wc)&63, d0+1.
            int n0r = n0 - 1536;
            int h0 = n0r >> 6;
            int wc = tid & 63;
            int seg = tid >> 2 >> 4;          // tid>>6: 0..3, 32 rows each
            int h = h0 + (wc >> 5);
            int d0 = (2 * wc) & 63;
            int b = m0 >> 10, t0r = m0 & 1023;
            uint32_t wlo[16], whi[16];
#pragma unroll
            for (int j2 = 0; j2 < 16; j2++) {
                int mlA = seg * 32 + 2 * j2;
                int mlB = mlA + 1;
                uint32_t wa = LD[mlA * 64 + (wc ^ (((mlA >> 2) & 3) << 3))];
                uint32_t wb = LD[mlB * 64 + (wc ^ (((mlB >> 2) & 3) << 3))];
                wlo[j2] = (wa & 0xFFFFu) | (wb << 16);
                whi[j2] = (wa >> 16) | (wb & 0xFFFF0000u);
            }
            short* p0 = VT + ((size_t)(b * NH + h) * HD + d0) * TT + t0r + seg * 32;
            short* p1 = p0 + TT;   // d0+1 row
#pragma unroll
            for (int k = 0; k < 4; k++) {
                int4 v0, v1;
                __builtin_memcpy(&v0, &wlo[k * 4], 16);
                __builtin_memcpy(&v1, &whi[k * 4], 16);
                *(int4*)(p0 + k * 8) = v0;
                *(int4*)(p1 + k * 8) = v1;
            }
        } else {
            // Q/K strips: coalesced 16B scatter stores (unchanged).
#pragma unroll
            for (int p = 0; p < 8; p++) {
                int ml = p * 16 + (tid >> 4);
                int wc = (tid & 15) * 4;
                int4 dat = *(const int4*)&LD[ml * 64 + (wc ^ (((ml >> 2) & 3) << 3))];
                int n = n0 + wc * 2;
                int part = (n >= 768) ? 1 : 0;
                int rem = n - part * 768;
                int h = rem >> 6, d = rem & 63;
                int m = m0 + ml, b = m >> 10, t = m & 1023;
                short* dst = (part == 0 ? Qb : Kb)
                             + (((size_t)b * NH + h) * TT + t) * HD + d;
                *(int4*)dst = dat;
            }
        }
    } else {
        // EPI1: bias + fp32 LDS repack (swizzled) -> dwordx4 stores
        float* LDf = (float*)smem_s;   // 64 KB = [128][128] fp32
#pragma unroll
        for (int mi = 0; mi < 4; mi++)
#pragma unroll
            for (int ni = 0; ni < 4; ni++) {
                int nl = wn * 64 + ni * 16 + c;
                float bv = bias[n0 + nl];
#pragma unroll
                for (int r = 0; r < 4; r++) {
                    int ml = wm * 64 + mi * 16 + g * 4 + r;
                    LDf[ml * 128 + (nl ^ (r << 3))] = acc[mi][ni][r] + bv;
                }
            }
        __syncthreads();
#pragma unroll
        for (int p = 0; p < 8; p++) {
            int ml = p * 16 + (tid >> 4);
            int rr = (ml & 3) << 3;
            int wc4 = (tid & 15) * 8;
            const float* rp = &LDf[ml * 128 + (wc4 ^ rr)];
            float4 f0 = *(const float4*)rp;
            float4 f1 = *(const float4*)(rp + 4);
            float* dst = out + (size_t)(m0 + ml) * CC + n0 + wc4;
            *(float4*)dst = f0;
            *(float4*)(dst + 4) = f1;
        }
    }
#undef LOAD
#undef WRITE
#undef COMPUTE
}

// ---------------------------------------------------------------- flash attention
// (unchanged — passed 8x; swapped-operand S^T = mfma(K,Q), lane-local softmax,
// per-wave barrier-free LDS P-tile, V from global VT, LDS O^T epilogue)
__global__ __launch_bounds__(256)
void attn_kernel(const short* __restrict__ Qb, const short* __restrict__ Kb,
                 const short* __restrict__ VT, short* __restrict__ Ob) {
    __shared__ uint32_t Pt[4][32][32];  // 16 KB per-wave P tile, XOR-swizzled
    __shared__ uint32_t ot[128 * 32];   // 16 KB epilogue O^T transpose
    const int tid = threadIdx.x, lane = tid & 63, wid = tid >> 6;
    const int g = lane >> 4, c = lane & 15;
    const int bh = blockIdx.x, qb = 7 - (int)blockIdx.y;
    const int b = bh / NH, h = bh % NH;
    const short* Qp = Qb + (size_t)bh * TT * HD;
    const short* Kp = Kb + (size_t)bh * TT * HD;
    const short* Vp = VT + (size_t)bh * TT * HD;
    const int q0 = qb * 128 + wid * 32;
    const int sw = (c & 7) << 2;

    bf16x8 qf[2][2];
#pragma unroll
    for (int qs = 0; qs < 2; qs++)
#pragma unroll
        for (int kh = 0; kh < 2; kh++)
            qf[qs][kh] = *(const bf16x8*)(Qp + (size_t)(q0 + qs * 16 + c) * HD + kh * 32 + g * 8);

    const f32x4 zero4 = {0.f, 0.f, 0.f, 0.f};
    f32x4 o[2][4];
#pragma unroll
    for (int qs = 0; qs < 2; qs++)
#pragma unroll
        for (int dt = 0; dt < 4; dt++) o[qs][dt] = zero4;
    float mrun[2] = {-1e30f, -1e30f}, lrun[2] = {0.f, 0.f};

    const int t0max = ((q0 + 31) >> 6) << 6;
    for (int t0 = 0; t0 <= t0max; t0 += 64) {
        f32x4 st[2][4];
#pragma unroll
        for (int nt = 0; nt < 4; nt++) {
            const short* kp = Kp + (size_t)(t0 + nt * 16 + c) * HD + g * 8;
            bf16x8 k0 = *(const bf16x8*)kp;
            bf16x8 k1 = *(const bf16x8*)(kp + 32);
#pragma unroll
            for (int qs = 0; qs < 2; qs++) {
                f32x4 z = zero4;
                z = __builtin_amdgcn_mfma_f32_16x16x32_bf16(k0, qf[qs][0], z, 0, 0, 0);
                z = __builtin_amdgcn_mfma_f32_16x16x32_bf16(k1, qf[qs][1], z, 0, 0, 0);
                st[qs][nt] = z;
            }
        }
        bf16x8 vf[2][4];
#pragma unroll
        for (int blk = 0; blk < 2; blk++)
#pragma unroll
            for (int dt = 0; dt < 4; dt++)
                vf[blk][dt] = *(const bf16x8*)(Vp + (size_t)(dt * 16 + c) * TT + t0 + blk * 32 + g * 8);
        if (t0 + 63 > q0) {
#pragma unroll
            for (int qs = 0; qs < 2; qs++) {
                int q = q0 + qs * 16 + c;
#pragma unroll
                for (int nt = 0; nt < 4; nt++)
#pragma unroll
                    for (int r = 0; r < 4; r++)
                        if (t0 + nt * 16 + g * 4 + r > q) st[qs][nt][r] = -1e30f;
            }
        }
#pragma unroll
        for (int qs = 0; qs < 2; qs++) {
            float mx = st[qs][0][0];
#pragma unroll
            for (int nt = 0; nt < 4; nt++)
#pragma unroll
                for (int r = 0; r < 4; r++) mx = fmaxf(mx, st[qs][nt][r]);
            mx = fmaxf(mx, __shfl_xor(mx, 16));
            mx = fmaxf(mx, __shfl_xor(mx, 32));
            float mnew = fmaxf(mrun[qs], mx);
            float al = __expf(mrun[qs] - mnew);
            mrun[qs] = mnew;
            float sm = 0.f;
#pragma unroll
            for (int nt = 0; nt < 4; nt++)
#pragma unroll
                for (int r = 0; r < 4; r++) {
                    float e = __expf(st[qs][nt][r] - mnew);
                    st[qs][nt][r] = e;
                    sm += e;
                }
            sm += __shfl_xor(sm, 16);
            sm += __shfl_xor(sm, 32);
            lrun[qs] = lrun[qs] * al + sm;
#pragma unroll
            for (int dt = 0; dt < 4; dt++) {
                o[qs][dt][0] *= al; o[qs][dt][1] *= al;
                o[qs][dt][2] *= al; o[qs][dt][3] *= al;
            }
            int row = qs * 16 + c;
#pragma unroll
            for (int nt = 0; nt < 4; nt++) {
                uint32_t w0 = bfpack(st[qs][nt][0], st[qs][nt][1]);
                uint32_t w1 = bfpack(st[qs][nt][2], st[qs][nt][3]);
                int wa = nt * 8 + 2 * g;
                Pt[wid][row][wa ^ sw]       = w0;
                Pt[wid][row][(wa + 1) ^ sw] = w1;
            }
        }
#pragma unroll
        for (int qs = 0; qs < 2; qs++) {
            int row = qs * 16 + c;
#pragma unroll
            for (int blk = 0; blk < 2; blk++) {
                bf16x8 pf = *(const bf16x8*)&Pt[wid][row][(blk * 16 + 4 * g) ^ sw];
#pragma unroll
                for (int dt = 0; dt < 4; dt++)
                    o[qs][dt] = __builtin_amdgcn_mfma_f32_16x16x32_bf16(
                        vf[blk][dt], pf, o[qs][dt], 0, 0, 0);
            }
        }
    }

#pragma unroll
    for (int qs = 0; qs < 2; qs++) {
        float inv = 1.0f / lrun[qs];
        int ql = wid * 32 + qs * 16 + c;
#pragma unroll
        for (int dt = 0; dt < 4; dt++) {
            uint32_t w0 = bfpack(o[qs][dt][0] * inv, o[qs][dt][1] * inv);
            uint32_t w1 = bfpack(o[qs][dt][2] * inv, o[qs][dt][3] * inv);
            int jc0 = dt * 8 + 2 * g;
            int jc1 = jc0 + 1;
            ot[ql * 32 + ((((jc0 >> 2) ^ (c & 7)) << 2) | (jc0 & 3))] = w0;
            ot[ql * 32 + ((((jc1 >> 2) ^ (c & 7)) << 2) | (jc1 & 3))] = w1;
        }
    }
    __syncthreads();
#pragma unroll
    for (int p = 0; p < 4; p++) {
        int q = (tid >> 3) + 32 * p;
        int jb = tid & 7;
        const uint32_t* src = &ot[q * 32 + ((jb ^ (q & 7)) << 2)];
        int4 w = *(const int4*)src;
        *(int4*)(Ob + ((size_t)b * TT + qb * 128 + q) * CC + h * HD + jb * 8) = w;
    }
}

// ---------------------------------------------------------------- launch
extern "C" void kernel_launch(void* const* d_in, const int* in_sizes, int n_in,
                              void* d_out, int out_size, void* d_ws, size_t ws_size,
                              hipStream_t stream) {
    const float* x     = (const float*)d_in[0];
    const float* Wqkv  = (const float*)d_in[1];
    const float* bqkv  = (const float*)d_in[2];
    const float* Wproj = (const float*)d_in[3];
    const float* bproj = (const float*)d_in[4];
    // d_in[5] = mask: causal by construction, unused

    char* ws = (char*)d_ws;
    // ws layout: WqkvT 3538944 | WprojT 1179648 | fc 262144 | Qb | Kb | VOb | VbT
    // xb (bf16 x) aliases VOb: xb consumed by gemm1; attn writes O there later.
    // VbT is written directly by gemm1's fused V-transpose epilogue.
    short*  WqkvT  = (short*)(ws);
    short*  WprojT = (short*)(ws + 3538944);
    float2* fc     = (float2*)(ws + 3538944 + 1179648);
    short*  Qb     = (short*)(ws + 4980736);
    short*  Kb     = (short*)(ws + 4980736 + 1 * 12582912);
    short*  VOb    = (short*)(ws + 4980736 + 2 * 12582912);  // xb, then O after attn
    short*  VbT    = (short*)(ws + 4980736 + 3 * 12582912);
    short*  xb     = VOb;
    float*  out    = (float*)d_out;

    hipLaunchKernelGGL(prep_kernel, dim3(5504), dim3(256), 0, stream,
                       x, Wqkv, Wproj, WqkvT, WprojT, xb, fc);
    hipLaunchKernelGGL((gemm_kernel<0>), dim3(18, 64), dim3(256), 0, stream,
                       xb, WqkvT, bqkv, Qb, Kb, VbT, fc, (float*)nullptr);
    hipLaunchKernelGGL(attn_kernel, dim3(96, 8), dim3(256), 0, stream, Qb, Kb, VbT, VOb);
    hipLaunchKernelGGL((gemm_kernel<1>), dim3(6, 64), dim3(256), 0, stream,
                       VOb, WprojT, bproj,
                       (short*)nullptr, (short*)nullptr, (short*)nullptr,
                       (const float2*)nullptr, out);
}